// Round 2
// baseline (614.512 us; speedup 1.0000x reference)
//
#include <hip/hip_runtime.h>

// ChildSumTreeLSTM on a static 4-ary heap tree.
// N=8192 nodes, H=256, D=300, V=50000, K=4, OUT=4.
// Leaves = nodes 2048..8191 (no children). Internal = 0..2047, 7 levels.
// Workspace layout (needs 48 MiB):
//   gx  : [8192][1024] f32  (node-major, col = g*256+h, gate order i,f,o,u)
//   Hb  : [8192][256]  f32
//   Cb  : [8192][256]  f32

#define N_NODES 8192
#define HDIM 256
#define DDIM 300
#define GXC 1024          // 4*HDIM
#define LEAF_FIRST 2048

__device__ __forceinline__ float sigf(float x) { return 1.0f / (1.0f + __expf(-x)); }

__device__ __forceinline__ float dot4(float acc, float4 a, float4 b) {
    acc = fmaf(a.x, b.x, acc);
    acc = fmaf(a.y, b.y, acc);
    acc = fmaf(a.z, b.z, acc);
    acc = fmaf(a.w, b.w, acc);
    return acc;
}

// ---------- Kernel 1: gx[n][c] = sum_d emb[xs[n]][d] * Wx[c][d] + bx[c] ------
// Wx viewed as [1024][300] (row-major: (g*H+h)*D + d). Classic 64x64x16 tile.
__global__ __launch_bounds__(256) void gx_gemm(
    const int* __restrict__ xs, const float* __restrict__ emb,
    const float* __restrict__ Wx, const float* __restrict__ bx,
    float* __restrict__ gx)
{
    __shared__ __align__(16) float As[16][68];   // [k][node]   (+4 pad)
    __shared__ __align__(16) float Bs[16][68];   // [k][col]
    const int tid  = threadIdx.x;
    const int n0   = blockIdx.y * 64;
    const int c0   = blockIdx.x * 64;
    const int sr   = tid >> 2;          // 0..63  staging row
    const int sk   = (tid & 3) << 2;    // 0,4,8,12 staging k
    const int trow = (tid >> 4) << 2;   // compute row base
    const int tcol = (tid & 15) << 2;   // compute col base

    const long arow = (long)xs[n0 + sr] * DDIM;
    const long brow = (long)(c0 + sr) * DDIM;

    float acc[4][4] = {};

    for (int k0 = 0; k0 < DDIM; k0 += 16) {   // 19 iters; 300 = 18*16 + 12
        float4 av, bv;
        if (k0 + sk < DDIM) {                 // 300 % 4 == 0 -> float4 always whole
            av = *(const float4*)(emb + arow + k0 + sk);
            bv = *(const float4*)(Wx  + brow + k0 + sk);
        } else {
            av = make_float4(0.f, 0.f, 0.f, 0.f);
            bv = make_float4(0.f, 0.f, 0.f, 0.f);
        }
        __syncthreads();                      // WAR: prior iter's reads done
        As[sk+0][sr] = av.x; As[sk+1][sr] = av.y; As[sk+2][sr] = av.z; As[sk+3][sr] = av.w;
        Bs[sk+0][sr] = bv.x; Bs[sk+1][sr] = bv.y; Bs[sk+2][sr] = bv.z; Bs[sk+3][sr] = bv.w;
        __syncthreads();                      // RAW
        #pragma unroll
        for (int k = 0; k < 16; k++) {
            float4 a = *(const float4*)&As[k][trow];
            float4 b = *(const float4*)&Bs[k][tcol];
            float avv[4] = {a.x, a.y, a.z, a.w};
            float bvv[4] = {b.x, b.y, b.z, b.w};
            #pragma unroll
            for (int i = 0; i < 4; i++)
                #pragma unroll
                for (int j = 0; j < 4; j++)
                    acc[i][j] = fmaf(avv[i], bvv[j], acc[i][j]);
        }
    }

    #pragma unroll
    for (int i = 0; i < 4; i++) {
        const int col = c0 + tcol;
        float4 r;
        r.x = acc[i][0] + bx[col + 0];
        r.y = acc[i][1] + bx[col + 1];
        r.z = acc[i][2] + bx[col + 2];
        r.w = acc[i][3] + bx[col + 3];
        *(float4*)(gx + (long)(n0 + trow + i) * GXC + col) = r;
    }
}

// ---------- Kernel 2: leaves (nodes 2048..8191) — pure elementwise ----------
__global__ __launch_bounds__(256) void leaf_kernel(
    const float* __restrict__ gx, const float* __restrict__ bh,
    float* __restrict__ Hb, float* __restrict__ Cb)
{
    const int node = LEAF_FIRST + blockIdx.x;
    const int t = threadIdx.x;
    const float* g = gx + (long)node * GXC;
    const float gi = g[t]       + bh[t];         // gate 0 = i
    const float go = g[512 + t] + bh[512 + t];   // gate 2 = o
    const float gu = g[768 + t] + bh[768 + t];   // gate 3 = u
    const float c  = sigf(gi) * tanhf(gu);
    const float h  = sigf(go) * tanhf(c);
    Hb[(long)node * HDIM + t] = h;
    Cb[(long)node * HDIM + t] = c;
}

// ---------- Kernel 3: one internal level; one block per node ----------------
__global__ __launch_bounds__(256) void tree_internal(
    int first, const float* __restrict__ gx, const int* __restrict__ child_idx,
    const float* __restrict__ child_mask, const float* __restrict__ Wh,
    const float* __restrict__ bh, float* __restrict__ Hb, float* __restrict__ Cb)
{
    const int node = first + blockIdx.x;
    const int t = threadIdx.x;
    __shared__ __align__(16) float sh_hs[HDIM];
    __shared__ __align__(16) float sh_hc[4][HDIM];

    int   ci[4];
    float cm[4], ccv[4];
    #pragma unroll
    for (int k = 0; k < 4; k++) {
        ci[k] = child_idx[node * 4 + k];
        cm[k] = child_mask[node * 4 + k];
    }
    float hsum = 0.f;
    #pragma unroll
    for (int k = 0; k < 4; k++) {
        float hv = 0.f, cv = 0.f;
        if (cm[k] != 0.f) {                    // block-uniform branch
            hv = Hb[(long)ci[k] * HDIM + t];
            cv = Cb[(long)ci[k] * HDIM + t];
        }
        sh_hc[k][t] = hv;
        ccv[k] = cv;
        hsum += hv;
    }
    sh_hs[t] = hsum;
    __syncthreads();

    // 7 dot products of length 256: rows t of Wh_i/Wh_o/Wh_u vs hs,
    // row t of Wh_f vs each child's h.
    const float* wi = Wh + 0 * 65536 + t * HDIM;
    const float* wf = Wh + 1 * 65536 + t * HDIM;
    const float* wo = Wh + 2 * 65536 + t * HDIM;
    const float* wu = Wh + 3 * 65536 + t * HDIM;
    float di = 0.f, dxo = 0.f, du = 0.f;
    float df[4] = {0.f, 0.f, 0.f, 0.f};
    #pragma unroll 2
    for (int j = 0; j < HDIM; j += 4) {
        const float4 hsv = *(const float4*)&sh_hs[j];
        const float4 h0  = *(const float4*)&sh_hc[0][j];
        const float4 h1  = *(const float4*)&sh_hc[1][j];
        const float4 h2  = *(const float4*)&sh_hc[2][j];
        const float4 h3  = *(const float4*)&sh_hc[3][j];
        const float4 wiv = *(const float4*)(wi + j);
        const float4 wfv = *(const float4*)(wf + j);
        const float4 wov = *(const float4*)(wo + j);
        const float4 wuv = *(const float4*)(wu + j);
        di    = dot4(di,    wiv, hsv);
        dxo   = dot4(dxo,   wov, hsv);
        du    = dot4(du,    wuv, hsv);
        df[0] = dot4(df[0], wfv, h0);
        df[1] = dot4(df[1], wfv, h1);
        df[2] = dot4(df[2], wfv, h2);
        df[3] = dot4(df[3], wfv, h3);
    }

    const float* g = gx + (long)node * GXC;
    const float gi = g[t]       + bh[t]       + di;    // i
    const float gf = g[256 + t] + bh[256 + t];         // f (per-child adds df[k])
    const float go = g[512 + t] + bh[512 + t] + dxo;   // o
    const float gu = g[768 + t] + bh[768 + t] + du;    // u

    float c = sigf(gi) * tanhf(gu);
    #pragma unroll
    for (int k = 0; k < 4; k++)
        if (cm[k] != 0.f)
            c = fmaf(sigf(gf + df[k]), ccv[k], c);
    const float h = sigf(go) * tanhf(c);
    Hb[(long)node * HDIM + t] = h;
    Cb[(long)node * HDIM + t] = c;
}

// ---------- Kernel 4: logits = Wout @ h_root + bout; log_softmax ------------
__global__ __launch_bounds__(256) void out_kernel(
    const float* __restrict__ Hb, const float* __restrict__ Wout,
    const float* __restrict__ bout, float* __restrict__ out)
{
    const int tid = threadIdx.x;
    const int o = tid >> 6;        // wave id = output row
    const int lane = tid & 63;
    float s = 0.f;
    for (int j = lane; j < HDIM; j += 64)
        s = fmaf(Wout[o * HDIM + j], Hb[j], s);
    #pragma unroll
    for (int off = 32; off > 0; off >>= 1)
        s += __shfl_down(s, off, 64);
    __shared__ float logits[4];
    if (lane == 0) logits[o] = s + bout[o];
    __syncthreads();
    if (tid == 0) {
        float m = logits[0];
        #pragma unroll
        for (int i = 1; i < 4; i++) m = fmaxf(m, logits[i]);
        float se = 0.f;
        #pragma unroll
        for (int i = 0; i < 4; i++) se += __expf(logits[i] - m);
        const float lse = m + __logf(se);
        #pragma unroll
        for (int i = 0; i < 4; i++) out[i] = logits[i] - lse;
    }
}

extern "C" void kernel_launch(void* const* d_in, const int* in_sizes, int n_in,
                              void* d_out, int out_size, void* d_ws, size_t ws_size,
                              hipStream_t stream)
{
    const int*   xs         = (const int*)  d_in[0];
    const int*   child_idx  = (const int*)  d_in[1];
    const float* child_mask = (const float*)d_in[2];
    const float* emb        = (const float*)d_in[3];
    const float* Wx         = (const float*)d_in[4];
    const float* bx         = (const float*)d_in[5];
    const float* Wh         = (const float*)d_in[6];
    const float* bh         = (const float*)d_in[7];
    const float* Wout       = (const float*)d_in[8];
    const float* bout       = (const float*)d_in[9];
    float* out = (float*)d_out;

    float* gxb = (float*)d_ws;                         // 33.5 MB
    float* Hb  = gxb + (size_t)N_NODES * GXC;          //  8.4 MB
    float* Cb  = Hb  + (size_t)N_NODES * HDIM;         //  8.4 MB  (total 48 MB)

    gx_gemm<<<dim3(GXC / 64, N_NODES / 64), 256, 0, stream>>>(xs, emb, Wx, bx, gxb);
    leaf_kernel<<<N_NODES - LEAF_FIRST, 256, 0, stream>>>(gxb, bh, Hb, Cb);

    // Internal levels, leaves-upward: [first, first+count)
    const int pf[7] = {1365, 341, 85, 21, 5, 1, 0};
    const int pc[7] = { 683, 1024, 256, 64, 16, 4, 1};
    for (int p = 0; p < 7; p++)
        tree_internal<<<pc[p], 256, 0, stream>>>(pf[p], gxb, child_idx, child_mask,
                                                 Wh, bh, Hb, Cb);

    out_kernel<<<1, 256, 0, stream>>>(Hb, Wout, bout, out);
}

// Round 3
// 386.951 us; speedup vs baseline: 1.5881x; 1.5881x over previous
//
#include <hip/hip_runtime.h>

// ChildSumTreeLSTM on a static 4-ary heap tree.
// N=8192, H=256, D=300, K=4, OUT=4. Leaves = 2048..8191. Internal 0..2047 in 7 levels.
// Workspace (50.3 MB, same as proven round):
//   gx : [8192][1024] f32   (gate order i,f,o,u)
//   Hb : [8192][256]  f32
//   Cb : [8192][256]  f32
// D (level-GEMM output, <=7.3 MB) aliases gx rows 2048.. (dead after leaf_kernel).

#define N_NODES 8192
#define HDIM 256
#define DDIM 300
#define GXC 1024
#define LEAF_FIRST 2048
#define WH_STRIDE 65536   // 256*256

__device__ __forceinline__ float sigf(float x) { return 1.0f / (1.0f + __expf(-x)); }

// ---------- Kernel 1: gx[n][c] = emb[xs[n]] · Wx[c] + bx[c]  (64x64 tile) ----
__global__ __launch_bounds__(256) void gx_gemm(
    const int* __restrict__ xs, const float* __restrict__ emb,
    const float* __restrict__ Wx, const float* __restrict__ bx,
    float* __restrict__ gx)
{
    __shared__ __align__(16) float As[16][68];
    __shared__ __align__(16) float Bs[16][68];
    const int tid  = threadIdx.x;
    const int n0   = blockIdx.y * 64;
    const int c0   = blockIdx.x * 64;
    const int sr   = tid >> 2;
    const int sk   = (tid & 3) << 2;
    const int trow = (tid >> 4) << 2;
    const int tcol = (tid & 15) << 2;

    const long arow = (long)xs[n0 + sr] * DDIM;
    const long brow = (long)(c0 + sr) * DDIM;

    float acc[4][4] = {};

    for (int k0 = 0; k0 < DDIM; k0 += 16) {
        float4 av, bv;
        if (k0 + sk < DDIM) {
            av = *(const float4*)(emb + arow + k0 + sk);
            bv = *(const float4*)(Wx  + brow + k0 + sk);
        } else {
            av = make_float4(0.f, 0.f, 0.f, 0.f);
            bv = make_float4(0.f, 0.f, 0.f, 0.f);
        }
        __syncthreads();
        As[sk+0][sr] = av.x; As[sk+1][sr] = av.y; As[sk+2][sr] = av.z; As[sk+3][sr] = av.w;
        Bs[sk+0][sr] = bv.x; Bs[sk+1][sr] = bv.y; Bs[sk+2][sr] = bv.z; Bs[sk+3][sr] = bv.w;
        __syncthreads();
        #pragma unroll
        for (int k = 0; k < 16; k++) {
            float4 a = *(const float4*)&As[k][trow];
            float4 b = *(const float4*)&Bs[k][tcol];
            float avv[4] = {a.x, a.y, a.z, a.w};
            float bvv[4] = {b.x, b.y, b.z, b.w};
            #pragma unroll
            for (int i = 0; i < 4; i++)
                #pragma unroll
                for (int j = 0; j < 4; j++)
                    acc[i][j] = fmaf(avv[i], bvv[j], acc[i][j]);
        }
    }

    #pragma unroll
    for (int i = 0; i < 4; i++) {
        const int col = c0 + tcol;
        float4 r;
        r.x = acc[i][0] + bx[col + 0];
        r.y = acc[i][1] + bx[col + 1];
        r.z = acc[i][2] + bx[col + 2];
        r.w = acc[i][3] + bx[col + 3];
        *(float4*)(gx + (long)(n0 + trow + i) * GXC + col) = r;
    }
}

// ---------- Kernel 2: leaves — pure elementwise -----------------------------
__global__ __launch_bounds__(256) void leaf_kernel(
    const float* __restrict__ gx, const float* __restrict__ bh,
    float* __restrict__ Hb, float* __restrict__ Cb)
{
    const int node = LEAF_FIRST + blockIdx.x;
    const int t = threadIdx.x;
    const float* g = gx + (long)node * GXC;
    const float gi = g[t]       + bh[t];
    const float go = g[512 + t] + bh[512 + t];
    const float gu = g[768 + t] + bh[768 + t];
    const float c  = sigf(gi) * tanhf(gu);
    const float h  = sigf(go) * tanhf(c);
    Hb[(long)node * HDIM + t] = h;
    Cb[(long)node * HDIM + t] = c;
}

// ---------- Kernel 3: per-level GEMM  D[sec][nl][r] = Wh_g[r,:]·X[nl,:] ------
// blockIdx.y = sec: 0=i (X=hs), 1=o (X=hs), 2=u (X=hs), 3..6=f child c (X=h_c)
// blockIdx.x = 64-col tile over nodes; blockIdx.z = 64-row tile (4 of them).
__global__ __launch_bounds__(256) void level_gemm(
    int first, int M, const float* __restrict__ Hb,
    const int* __restrict__ child_idx, const float* __restrict__ child_mask,
    const float* __restrict__ Wh, float* __restrict__ D)
{
    __shared__ __align__(16) float Xs[16][68];
    __shared__ __align__(16) float Ws[16][68];
    const int tid  = threadIdx.x;
    const int sec  = blockIdx.y;
    const int c0   = blockIdx.x * 64;
    const int r0   = blockIdx.z * 64;
    const int sr   = tid >> 2;
    const int sk   = (tid & 3) << 2;
    const int trow = (tid >> 4) << 2;
    const int tcol = (tid & 15) << 2;

    const float* Wg;
    if      (sec == 0) Wg = Wh;                  // i
    else if (sec == 1) Wg = Wh + 2 * WH_STRIDE;  // o
    else if (sec == 2) Wg = Wh + 3 * WH_STRIDE;  // u
    else               Wg = Wh + 1 * WH_STRIDE;  // f

    // Column (node) this thread stages:
    const int  nl    = c0 + sr;
    const bool valid = nl < M;
    int   ci[4];
    float cm[4] = {0.f, 0.f, 0.f, 0.f};
    if (valid) {
        const int n = first + nl;
        if (sec < 3) {
            #pragma unroll
            for (int k = 0; k < 4; k++) {
                ci[k] = child_idx[n * 4 + k];
                cm[k] = child_mask[n * 4 + k];
            }
        } else {
            ci[0] = child_idx[n * 4 + (sec - 3)];
            cm[0] = child_mask[n * 4 + (sec - 3)];
        }
    }
    const long wrow = (long)(r0 + sr) * HDIM;

    float acc[4][4] = {};

    for (int k0 = 0; k0 < HDIM; k0 += 16) {
        float4 xv = make_float4(0.f, 0.f, 0.f, 0.f);
        if (valid) {
            if (sec < 3) {
                #pragma unroll
                for (int k = 0; k < 4; k++)
                    if (cm[k] != 0.f) {
                        const float4 hv = *(const float4*)(Hb + ci[k] * HDIM + k0 + sk);
                        xv.x += hv.x; xv.y += hv.y; xv.z += hv.z; xv.w += hv.w;
                    }
            } else if (cm[0] != 0.f) {
                xv = *(const float4*)(Hb + ci[0] * HDIM + k0 + sk);
            }
        }
        const float4 wv = *(const float4*)(Wg + wrow + k0 + sk);
        __syncthreads();
        Xs[sk+0][sr] = xv.x; Xs[sk+1][sr] = xv.y; Xs[sk+2][sr] = xv.z; Xs[sk+3][sr] = xv.w;
        Ws[sk+0][sr] = wv.x; Ws[sk+1][sr] = wv.y; Ws[sk+2][sr] = wv.z; Ws[sk+3][sr] = wv.w;
        __syncthreads();
        #pragma unroll
        for (int k = 0; k < 16; k++) {
            float4 a = *(const float4*)&Ws[k][trow];
            float4 b = *(const float4*)&Xs[k][tcol];
            float avv[4] = {a.x, a.y, a.z, a.w};
            float bvv[4] = {b.x, b.y, b.z, b.w};
            #pragma unroll
            for (int i = 0; i < 4; i++)
                #pragma unroll
                for (int j = 0; j < 4; j++)
                    acc[i][j] = fmaf(avv[i], bvv[j], acc[i][j]);
        }
    }

    #pragma unroll
    for (int j = 0; j < 4; j++) {
        const int col = c0 + tcol + j;
        if (col < M) {
            float4 r;
            r.x = acc[0][j]; r.y = acc[1][j]; r.z = acc[2][j]; r.w = acc[3][j];
            *(float4*)(D + ((long)(sec * M + col)) * HDIM + r0 + trow) = r;
        }
    }
}

// ---------- Kernel 4: per-level pointwise — combine D + gx -> h, c ----------
__global__ __launch_bounds__(256) void level_pointwise(
    int first, int M, const float* __restrict__ gx, const float* __restrict__ D,
    const int* __restrict__ child_idx, const float* __restrict__ child_mask,
    const float* __restrict__ bh, float* __restrict__ Hb, float* __restrict__ Cb)
{
    const int nl = blockIdx.x;
    const int n  = first + nl;
    const int t  = threadIdx.x;
    const float di  = D[((long)(0 * M + nl)) * HDIM + t];
    const float dO  = D[((long)(1 * M + nl)) * HDIM + t];
    const float du  = D[((long)(2 * M + nl)) * HDIM + t];
    const float* g = gx + (long)n * GXC;
    const float gi  = g[t]       + bh[t]       + di;
    const float gfb = g[256 + t] + bh[256 + t];
    const float go  = g[512 + t] + bh[512 + t] + dO;
    const float gu  = g[768 + t] + bh[768 + t] + du;

    float c = sigf(gi) * tanhf(gu);
    #pragma unroll
    for (int k = 0; k < 4; k++) {
        const float m = child_mask[n * 4 + k];
        if (m != 0.f) {
            const float df = D[((long)((3 + k) * M + nl)) * HDIM + t];
            const float cc = Cb[(long)child_idx[n * 4 + k] * HDIM + t];
            c = fmaf(sigf(gfb + df), cc, c);
        }
    }
    const float h = sigf(go) * tanhf(c);
    Hb[(long)n * HDIM + t] = h;
    Cb[(long)n * HDIM + t] = c;
}

// ---------- Kernel 5: logits + log_softmax ----------------------------------
__global__ __launch_bounds__(256) void out_kernel(
    const float* __restrict__ Hb, const float* __restrict__ Wout,
    const float* __restrict__ bout, float* __restrict__ out)
{
    const int tid = threadIdx.x;
    const int o = tid >> 6;
    const int lane = tid & 63;
    float s = 0.f;
    for (int j = lane; j < HDIM; j += 64)
        s = fmaf(Wout[o * HDIM + j], Hb[j], s);
    #pragma unroll
    for (int off = 32; off > 0; off >>= 1)
        s += __shfl_down(s, off, 64);
    __shared__ float logits[4];
    if (lane == 0) logits[o] = s + bout[o];
    __syncthreads();
    if (tid == 0) {
        float m = logits[0];
        #pragma unroll
        for (int i = 1; i < 4; i++) m = fmaxf(m, logits[i]);
        float se = 0.f;
        #pragma unroll
        for (int i = 0; i < 4; i++) se += __expf(logits[i] - m);
        const float lse = m + __logf(se);
        #pragma unroll
        for (int i = 0; i < 4; i++) out[i] = logits[i] - lse;
    }
}

extern "C" void kernel_launch(void* const* d_in, const int* in_sizes, int n_in,
                              void* d_out, int out_size, void* d_ws, size_t ws_size,
                              hipStream_t stream)
{
    const int*   xs         = (const int*)  d_in[0];
    const int*   child_idx  = (const int*)  d_in[1];
    const float* child_mask = (const float*)d_in[2];
    const float* emb        = (const float*)d_in[3];
    const float* Wx         = (const float*)d_in[4];
    const float* bx         = (const float*)d_in[5];
    const float* Wh         = (const float*)d_in[6];
    const float* bh         = (const float*)d_in[7];
    const float* Wout       = (const float*)d_in[8];
    const float* bout       = (const float*)d_in[9];
    float* out = (float*)d_out;

    float* gxb = (float*)d_ws;
    float* Hb  = gxb + (size_t)N_NODES * GXC;
    float* Cb  = Hb  + (size_t)N_NODES * HDIM;
    // D aliases the gx rows of leaf nodes (dead after leaf_kernel).
    // Max size: 7*1024*256 floats = 7.3 MB << 6144*1024 floats available.
    float* Dbuf = gxb + (size_t)LEAF_FIRST * GXC;

    gx_gemm<<<dim3(GXC / 64, N_NODES / 64), 256, 0, stream>>>(xs, emb, Wx, bx, gxb);
    leaf_kernel<<<N_NODES - LEAF_FIRST, 256, 0, stream>>>(gxb, bh, Hb, Cb);

    const int pf[7] = {1365, 341, 85, 21, 5, 1, 0};
    const int pc[7] = { 683, 1024, 256, 64, 16, 4, 1};
    for (int p = 0; p < 7; p++) {
        const int M = pc[p];
        dim3 grid((M + 63) / 64, 7, 4);
        level_gemm<<<grid, 256, 0, stream>>>(pf[p], M, Hb, child_idx, child_mask,
                                             Wh, Dbuf);
        level_pointwise<<<M, 256, 0, stream>>>(pf[p], M, gxb, Dbuf, child_idx,
                                               child_mask, bh, Hb, Cb);
    }

    out_kernel<<<1, 256, 0, stream>>>(Hb, Wout, bout, out);
}